// Round 2
// baseline (1951.355 us; speedup 1.0000x reference)
//
#include <hip/hip_runtime.h>
#include <hip/hip_bf16.h>
#include <stdint.h>

#define TOK  4096
#define DIM  2048
#define HID  4096
#define ODIM 2048
#define NEXP 8
#define KSEL 5
#define KTOT (NEXP * HID)   // 32768
#define MAXROWS 21504       // 5*4096 active rows + tile-overrun pad

typedef __bf16 bf16x8 __attribute__((ext_vector_type(8)));
typedef float  f32x4  __attribute__((ext_vector_type(4)));

__device__ __forceinline__ uint16_t f2bf(float f) {
  uint32_t u = __float_as_uint(f);
  u += 0x7FFFu + ((u >> 16) & 1u);   // round-to-nearest-even
  return (uint16_t)(u >> 16);
}

#define GLD16(g, l) __builtin_amdgcn_global_load_lds(                      \
    (const __attribute__((address_space(1))) void*)(g),                    \
    (__attribute__((address_space(3))) void*)(l), 16, 0, 0)

// ---------------- small kernels ----------------

__global__ void zero_cnt_kernel(int* __restrict__ cnt) {
  if (threadIdx.x < NEXP) cnt[threadIdx.x] = 0;
}

__global__ void scan_kernel(const int* __restrict__ cnt, int* __restrict__ base) {
  if (threadIdx.x == 0) {
    int r = 0;
    for (int e = 0; e < NEXP; ++e) { base[e] = r; r += cnt[e]; }
  }
}

// out[n, :] = sum_e w[n,e] * b2[e, :]
__global__ void bias_init_kernel(const float* __restrict__ wts,
                                 const float* __restrict__ b2,
                                 float* __restrict__ out) {
  const int n = blockIdx.x;
  const int t = threadIdx.x;
  float w[NEXP];
#pragma unroll
  for (int e = 0; e < NEXP; ++e) w[e] = wts[n * NEXP + e];
#pragma unroll
  for (int g = 0; g < 2; ++g) {
    const int c = g * 1024 + t * 4;
    float4 s = make_float4(0.f, 0.f, 0.f, 0.f);
#pragma unroll
    for (int e = 0; e < NEXP; ++e) {
      const float4 bv = *(const float4*)(b2 + (size_t)e * ODIM + c);
      s.x += w[e] * bv.x; s.y += w[e] * bv.y;
      s.z += w[e] * bv.z; s.w += w[e] * bv.w;
    }
    *(float4*)(out + (size_t)n * ODIM + c) = s;
  }
}

// ---------------- convert kernels ----------------

__global__ void cast_x_kernel(const float* __restrict__ in,
                              uint16_t* __restrict__ out, int n4) {
  int i = blockIdx.x * blockDim.x + threadIdx.x;
  if (i >= n4) return;
  float4 v = ((const float4*)in)[i];
  ushort4 o;
  o.x = f2bf(v.x); o.y = f2bf(v.y); o.z = f2bf(v.z); o.w = f2bf(v.w);
  ((ushort4*)out)[i] = o;
}

// out[c*R + r] = bf16(in[r*C + c]), batched over blockIdx.z
__global__ void transpose_cast_kernel(const float* __restrict__ in,
                                      uint16_t* __restrict__ out,
                                      int R, int C, long inBatch, long outBatch) {
  __shared__ float tile[32][33];
  const float* src = in + (size_t)blockIdx.z * inBatch;
  uint16_t*    dst = out + (size_t)blockIdx.z * outBatch;
  int c0 = blockIdx.x * 32, r0 = blockIdx.y * 32;
  int tx = threadIdx.x, ty = threadIdx.y;   // (32, 8)
#pragma unroll
  for (int i = 0; i < 4; ++i)
    tile[ty + i * 8][tx] = src[(size_t)(r0 + ty + i * 8) * C + c0 + tx];
  __syncthreads();
#pragma unroll
  for (int i = 0; i < 4; ++i)
    dst[(size_t)(c0 + ty + i * 8) * R + r0 + tx] = f2bf(tile[tx][ty + i * 8]);
}

// ---------------- routing (+ per-expert token lists) ----------------

__global__ void routing_kernel(const float* __restrict__ x,
                               const float* __restrict__ Wg, const float* __restrict__ bg,
                               const float* __restrict__ Wa, const float* __restrict__ ba,
                               const float* __restrict__ Wb, const float* __restrict__ bb,
                               const float* __restrict__ sigs,
                               float* __restrict__ wts,
                               int* __restrict__ cnt, int* __restrict__ list) {
  const int n    = blockIdx.x;
  const int lane = threadIdx.x;   // 64
  const float* xr = x + (size_t)n * DIM;

  float ga[NEXP]; float aa[32];
#pragma unroll
  for (int e = 0; e < NEXP; ++e) ga[e] = 0.f;
#pragma unroll
  for (int j = 0; j < 32; ++j) aa[j] = 0.f;

  for (int it = 0; it < DIM / 64; ++it) {
    int d = it * 64 + lane;
    float xv = xr[d];
    const float* wgr = Wg + (size_t)d * NEXP;
#pragma unroll
    for (int e = 0; e < NEXP; ++e) ga[e] += xv * wgr[e];
    const float* war = Wa + (size_t)d * 32;
#pragma unroll
    for (int j = 0; j < 32; ++j) aa[j] += xv * war[j];
  }
#pragma unroll
  for (int s = 1; s < 64; s <<= 1) {
#pragma unroll
    for (int e = 0; e < NEXP; ++e) ga[e] += __shfl_xor(ga[e], s);
#pragma unroll
    for (int j = 0; j < 32; ++j) aa[j] += __shfl_xor(aa[j], s);
  }

  float ph[16];
#pragma unroll
  for (int i = 0; i < 16; ++i) ph[i] = bb[i];
#pragma unroll
  for (int j = 0; j < 32; ++j) {
    float a = aa[j] + ba[j];
    a = a > 0.f ? a : 0.f;
#pragma unroll
    for (int i = 0; i < 16; ++i) ph[i] += a * Wb[j * 16 + i];
  }
  float nrm = 0.f;
#pragma unroll
  for (int i = 0; i < 16; ++i) nrm += ph[i] * ph[i];
  nrm = fmaxf(sqrtf(nrm), 1e-12f);

  const float invT = 0.36787944117144233f;  // 1/e
  float lg[NEXP], mx = -1e30f;
#pragma unroll
  for (int e = 0; e < NEXP; ++e) { lg[e] = (ga[e] + bg[e]) * invT; mx = fmaxf(mx, lg[e]); }
  float psum = 0.f, pr[NEXP];
#pragma unroll
  for (int e = 0; e < NEXP; ++e) { pr[e] = expf(lg[e] - mx); psum += pr[e]; }

  float eff[NEXP];
#pragma unroll
  for (int e = 0; e < NEXP; ++e) {
    const float* sg = sigs + e * 16;
    float dot = 0.f, sn = 0.f;
#pragma unroll
    for (int i = 0; i < 16; ++i) { dot += ph[i] * sg[i]; sn += sg[i] * sg[i]; }
    sn = fmaxf(sqrtf(sn), 1e-12f);
    float match = (dot / (nrm * sn) + 1.f) * 0.5f;
    eff[e] = (pr[e] / psum) * match;
  }

  int selmask = 0;
#pragma unroll
  for (int t = 0; t < KSEL; ++t) {
    int bi = 0; float bv = -1e30f;
#pragma unroll
    for (int e = 0; e < NEXP; ++e) {
      bool ok = !((selmask >> e) & 1);
      if (ok && eff[e] > bv) { bv = eff[e]; bi = e; }
    }
    selmask |= (1 << bi);
  }
  float wsum = 0.f, wv[NEXP];
#pragma unroll
  for (int e = 0; e < NEXP; ++e) {
    wv[e] = ((selmask >> e) & 1) ? eff[e] : 0.f;
    wsum += wv[e];
  }
  float inv = 1.f / (wsum + 1e-8f);
  if (lane == 0) {
#pragma unroll
    for (int e = 0; e < NEXP; ++e) wts[n * NEXP + e] = wv[e] * inv;
#pragma unroll
    for (int e = 0; e < NEXP; ++e) {
      if ((selmask >> e) & 1) {
        int p = atomicAdd(&cnt[e], 1);
        list[e * TOK + p] = n;
      }
    }
  }
}

// ---------------- GEMM1: per expert, gathered rows ----------------
// hbuf[base[e]+p, col] = bf16( w[n,e] * relu( x[n,:] @ W1[e][:,col] + b1[e,col] ) )

__global__ void gemm1_kernel(const uint16_t* __restrict__ xbf,
                             const uint16_t* __restrict__ W1T,
                             const int* __restrict__ cnt,
                             const int* __restrict__ base,
                             const int* __restrict__ list,
                             const float* __restrict__ wts,
                             const float* __restrict__ b1,
                             uint16_t* __restrict__ hbuf) {
  __shared__ __attribute__((aligned(16))) uint16_t smA[128 * 64];
  __shared__ __attribute__((aligned(16))) uint16_t smB[128 * 64];
  const int e  = blockIdx.z;
  const int ce = cnt[e];
  const int tileM = blockIdx.y * 128;
  if (tileM >= ce) return;
  const int be    = base[e];
  const int tileN = blockIdx.x * 128;
  const int tid = threadIdx.x, lane = tid & 63, wid = tid >> 6;
  const int wr = wid >> 1, wc = wid & 1;
  const int* liste = list + e * TOK;

  const uint16_t* srcA[4]; const uint16_t* srcB[4]; uint32_t lof[4];
#pragma unroll
  for (int j = 0; j < 4; ++j) {
    const int f   = (wid * 4 + j) * 64 + lane;
    const int row = f >> 3;
    const int s8  = (f & 7) ^ (row & 7);
    int p = tileM + row; p = p < ce ? p : ce - 1;
    srcA[j] = xbf + (size_t)liste[p] * DIM + s8 * 8;
    srcB[j] = W1T + ((size_t)e * HID + tileN + row) * DIM + s8 * 8;
    lof[j]  = (wid * 4 + j) * 1024;
  }

  f32x4 acc[4][4];
#pragma unroll
  for (int m = 0; m < 4; ++m)
#pragma unroll
    for (int n = 0; n < 4; ++n) acc[m][n] = (f32x4){0.f, 0.f, 0.f, 0.f};

  for (int k0 = 0; k0 < DIM; k0 += 64) {
#pragma unroll
    for (int j = 0; j < 4; ++j) {
      GLD16(srcA[j] + k0, (char*)smA + lof[j]);
      GLD16(srcB[j] + k0, (char*)smB + lof[j]);
    }
    __syncthreads();
#pragma unroll
    for (int kk = 0; kk < 2; ++kk) {
      bf16x8 av[4], bv[4];
#pragma unroll
      for (int m = 0; m < 4; ++m) {
        const int row = wr * 64 + m * 16 + (lane & 15);
        const int g   = (kk * 4 + (lane >> 4)) ^ (row & 7);
        av[m] = *(const bf16x8*)(smA + row * 64 + g * 8);
      }
#pragma unroll
      for (int n = 0; n < 4; ++n) {
        const int row = wc * 64 + n * 16 + (lane & 15);
        const int g   = (kk * 4 + (lane >> 4)) ^ (row & 7);
        bv[n] = *(const bf16x8*)(smB + row * 64 + g * 8);
      }
#pragma unroll
      for (int m = 0; m < 4; ++m)
#pragma unroll
        for (int n = 0; n < 4; ++n)
          acc[m][n] = __builtin_amdgcn_mfma_f32_16x16x32_bf16(av[m], bv[n], acc[m][n], 0, 0, 0);
    }
    __syncthreads();
  }

  const float* b1e = b1 + (size_t)e * HID;
#pragma unroll
  for (int m = 0; m < 4; ++m)
#pragma unroll
    for (int r = 0; r < 4; ++r) {
      const int p = tileM + wr * 64 + m * 16 + ((lane >> 4) << 2) + r;
      if (p < ce) {
        const int n = liste[p];
        const float w = wts[n * NEXP + e];
        uint16_t* orow = hbuf + (size_t)(be + p) * HID;
#pragma unroll
        for (int nf = 0; nf < 4; ++nf) {
          const int col = tileN + wc * 64 + nf * 16 + (lane & 15);
          float v = acc[m][nf][r] + b1e[col];
          v = v > 0.f ? v : 0.f;
          orow[col] = f2bf(v * w);
        }
      }
    }
}

// ---------------- GEMM2: per expert, scatter-accumulate into out ----------------
// out[n, col] += hbuf[base[e]+p, :] @ W2[e][:, col]

__global__ void gemm2_kernel(const uint16_t* __restrict__ hbuf,
                             const uint16_t* __restrict__ W2T,
                             const int* __restrict__ cnt,
                             const int* __restrict__ base,
                             const int* __restrict__ list,
                             float* __restrict__ out) {
  __shared__ __attribute__((aligned(16))) uint16_t smA[128 * 64];
  __shared__ __attribute__((aligned(16))) uint16_t smB[128 * 64];
  const int e  = blockIdx.z;
  const int ce = cnt[e];
  const int tileM = blockIdx.y * 128;
  if (tileM >= ce) return;
  const int be    = base[e];
  const int tileN = blockIdx.x * 128;
  const int tid = threadIdx.x, lane = tid & 63, wid = tid >> 6;
  const int wr = wid >> 1, wc = wid & 1;
  const int* liste = list + e * TOK;

  const uint16_t* srcA[4]; const uint16_t* srcB[4]; uint32_t lof[4];
#pragma unroll
  for (int j = 0; j < 4; ++j) {
    const int f   = (wid * 4 + j) * 64 + lane;
    const int row = f >> 3;
    const int s8  = (f & 7) ^ (row & 7);
    srcA[j] = hbuf + (size_t)(be + tileM + row) * HID + s8 * 8;
    srcB[j] = W2T + (size_t)(tileN + row) * KTOT + e * HID + s8 * 8;
    lof[j]  = (wid * 4 + j) * 1024;
  }

  f32x4 acc[4][4];
#pragma unroll
  for (int m = 0; m < 4; ++m)
#pragma unroll
    for (int n = 0; n < 4; ++n) acc[m][n] = (f32x4){0.f, 0.f, 0.f, 0.f};

  for (int k0 = 0; k0 < HID; k0 += 64) {
#pragma unroll
    for (int j = 0; j < 4; ++j) {
      GLD16(srcA[j] + k0, (char*)smA + lof[j]);
      GLD16(srcB[j] + k0, (char*)smB + lof[j]);
    }
    __syncthreads();
#pragma unroll
    for (int kk = 0; kk < 2; ++kk) {
      bf16x8 av[4], bv[4];
#pragma unroll
      for (int m = 0; m < 4; ++m) {
        const int row = wr * 64 + m * 16 + (lane & 15);
        const int g   = (kk * 4 + (lane >> 4)) ^ (row & 7);
        av[m] = *(const bf16x8*)(smA + row * 64 + g * 8);
      }
#pragma unroll
      for (int n = 0; n < 4; ++n) {
        const int row = wc * 64 + n * 16 + (lane & 15);
        const int g   = (kk * 4 + (lane >> 4)) ^ (row & 7);
        bv[n] = *(const bf16x8*)(smB + row * 64 + g * 8);
      }
#pragma unroll
      for (int m = 0; m < 4; ++m)
#pragma unroll
        for (int n = 0; n < 4; ++n)
          acc[m][n] = __builtin_amdgcn_mfma_f32_16x16x32_bf16(av[m], bv[n], acc[m][n], 0, 0, 0);
    }
    __syncthreads();
  }

#pragma unroll
  for (int m = 0; m < 4; ++m)
#pragma unroll
    for (int r = 0; r < 4; ++r) {
      const int p = tileM + wr * 64 + m * 16 + ((lane >> 4) << 2) + r;
      if (p < ce) {
        const int n = liste[p];
        float* orow = out + (size_t)n * ODIM;
#pragma unroll
        for (int nf = 0; nf < 4; ++nf) {
          const int col = tileN + wc * 64 + nf * 16 + (lane & 15);
          atomicAdd(orow + col, acc[m][nf][r]);
        }
      }
    }
}

// ---------------- launch ----------------

extern "C" void kernel_launch(void* const* d_in, const int* in_sizes, int n_in,
                              void* d_out, int out_size, void* d_ws, size_t ws_size,
                              hipStream_t stream) {
  const float* x    = (const float*)d_in[0];
  const float* Wg   = (const float*)d_in[1];
  const float* bg   = (const float*)d_in[2];
  const float* Wa   = (const float*)d_in[3];
  const float* ba   = (const float*)d_in[4];
  const float* Wb   = (const float*)d_in[5];
  const float* bb   = (const float*)d_in[6];
  const float* sigs = (const float*)d_in[7];
  const float* W1   = (const float*)d_in[8];
  const float* b1   = (const float*)d_in[9];
  const float* W2   = (const float*)d_in[10];
  const float* b2   = (const float*)d_in[11];
  float* out = (float*)d_out;

  char* ws = (char*)d_ws;
  float*    wts  = (float*)(ws + 0);            //   131072 B
  int*      cnt  = (int*)(ws + 131072);         //       32 B
  int*      base = (int*)(ws + 131104);         //       32 B
  int*      list = (int*)(ws + 135168);         //   131072 B
  uint16_t* xbf  = (uint16_t*)(ws + 266240);    // 16777216 B
  uint16_t* W1T  = (uint16_t*)(ws + 17043456);  // 134217728 B
  uint16_t* W2T  = (uint16_t*)(ws + 151261184); // 134217728 B
  uint16_t* hbuf = (uint16_t*)(ws + 285478912); // 176160768 B -> ends 461639680

  zero_cnt_kernel<<<1, 64, 0, stream>>>(cnt);
  cast_x_kernel<<<(TOK * DIM / 4) / 256, 256, 0, stream>>>(x, xbf, TOK * DIM / 4);
  transpose_cast_kernel<<<dim3(HID / 32, DIM / 32, NEXP), dim3(32, 8), 0, stream>>>(
      W1, W1T, DIM, HID, (long)DIM * HID, (long)DIM * HID);
  transpose_cast_kernel<<<dim3(ODIM / 32, KTOT / 32, 1), dim3(32, 8), 0, stream>>>(
      W2, W2T, KTOT, ODIM, 0, 0);
  routing_kernel<<<TOK, 64, 0, stream>>>(x, Wg, bg, Wa, ba, Wb, bb, sigs, wts, cnt, list);
  scan_kernel<<<1, 64, 0, stream>>>(cnt, base);
  bias_init_kernel<<<TOK, 256, 0, stream>>>(wts, b2, out);

  gemm1_kernel<<<dim3(HID / 128, TOK / 128, NEXP), 256, 0, stream>>>(
      xbf, W1T, cnt, base, list, wts, b1, hbuf);
  gemm2_kernel<<<dim3(ODIM / 128, TOK / 128, NEXP), 256, 0, stream>>>(
      hbuf, W2T, cnt, base, list, out);
}

// Round 3
// 1766.306 us; speedup vs baseline: 1.1048x; 1.1048x over previous
//
#include <hip/hip_runtime.h>
#include <hip/hip_bf16.h>
#include <stdint.h>

#define TOK  4096
#define DIM  2048
#define HID  4096
#define ODIM 2048
#define NEXP 8
#define KSEL 5
#define NSLOT (TOK * KSEL)   // 20480 — every token selects exactly 5 experts

typedef __bf16 bf16x8 __attribute__((ext_vector_type(8)));
typedef float  f32x4  __attribute__((ext_vector_type(4)));
typedef unsigned short ushort8 __attribute__((ext_vector_type(8)));

__device__ __forceinline__ uint16_t f2bf(float f) {
  uint32_t u = __float_as_uint(f);
  u += 0x7FFFu + ((u >> 16) & 1u);   // round-to-nearest-even
  return (uint16_t)(u >> 16);
}
__device__ __forceinline__ float bf2f(uint16_t h) {
  uint32_t u = ((uint32_t)h) << 16;
  return __uint_as_float(u);
}

#define GLD16(g, l) __builtin_amdgcn_global_load_lds(                      \
    (const __attribute__((address_space(1))) void*)(g),                    \
    (__attribute__((address_space(3))) void*)(l), 16, 0, 0)

// ---------------- convert kernels ----------------

__global__ void cast_x_kernel(const float* __restrict__ in,
                              uint16_t* __restrict__ out, int n4) {
  int i = blockIdx.x * blockDim.x + threadIdx.x;
  if (i >= n4) return;
  float4 v = ((const float4*)in)[i];
  ushort4 o;
  o.x = f2bf(v.x); o.y = f2bf(v.y); o.z = f2bf(v.z); o.w = f2bf(v.w);
  ((ushort4*)out)[i] = o;
}

// out[c*R + r] = bf16(in[r*C + c]), batched over blockIdx.z
__global__ void transpose_cast_kernel(const float* __restrict__ in,
                                      uint16_t* __restrict__ out,
                                      int R, int C, long inBatch, long outBatch) {
  __shared__ float tile[32][33];
  const float* src = in + (size_t)blockIdx.z * inBatch;
  uint16_t*    dst = out + (size_t)blockIdx.z * outBatch;
  int c0 = blockIdx.x * 32, r0 = blockIdx.y * 32;
  int tx = threadIdx.x, ty = threadIdx.y;   // (32, 8)
#pragma unroll
  for (int i = 0; i < 4; ++i)
    tile[ty + i * 8][tx] = src[(size_t)(r0 + ty + i * 8) * C + c0 + tx];
  __syncthreads();
#pragma unroll
  for (int i = 0; i < 4; ++i)
    dst[(size_t)(c0 + ty + i * 8) * R + r0 + tx] = f2bf(tile[tx][ty + i * 8]);
}

// ---------------- routing: weights + selection bitmask (pure, no atomics) ----------------

__global__ void routing_kernel(const float* __restrict__ x,
                               const float* __restrict__ Wg, const float* __restrict__ bg,
                               const float* __restrict__ Wa, const float* __restrict__ ba,
                               const float* __restrict__ Wb, const float* __restrict__ bb,
                               const float* __restrict__ sigs,
                               float* __restrict__ wts, int* __restrict__ selmask_g) {
  const int n    = blockIdx.x;
  const int lane = threadIdx.x;   // 64
  const float* xr = x + (size_t)n * DIM;

  float ga[NEXP]; float aa[32];
#pragma unroll
  for (int e = 0; e < NEXP; ++e) ga[e] = 0.f;
#pragma unroll
  for (int j = 0; j < 32; ++j) aa[j] = 0.f;

  for (int it = 0; it < DIM / 64; ++it) {
    int d = it * 64 + lane;
    float xv = xr[d];
    const float* wgr = Wg + (size_t)d * NEXP;
#pragma unroll
    for (int e = 0; e < NEXP; ++e) ga[e] += xv * wgr[e];
    const float* war = Wa + (size_t)d * 32;
#pragma unroll
    for (int j = 0; j < 32; ++j) aa[j] += xv * war[j];
  }
#pragma unroll
  for (int s = 1; s < 64; s <<= 1) {
#pragma unroll
    for (int e = 0; e < NEXP; ++e) ga[e] += __shfl_xor(ga[e], s);
#pragma unroll
    for (int j = 0; j < 32; ++j) aa[j] += __shfl_xor(aa[j], s);
  }

  float ph[16];
#pragma unroll
  for (int i = 0; i < 16; ++i) ph[i] = bb[i];
#pragma unroll
  for (int j = 0; j < 32; ++j) {
    float a = aa[j] + ba[j];
    a = a > 0.f ? a : 0.f;
#pragma unroll
    for (int i = 0; i < 16; ++i) ph[i] += a * Wb[j * 16 + i];
  }
  float nrm = 0.f;
#pragma unroll
  for (int i = 0; i < 16; ++i) nrm += ph[i] * ph[i];
  nrm = fmaxf(sqrtf(nrm), 1e-12f);

  const float invT = 0.36787944117144233f;  // 1/e
  float lg[NEXP], mx = -1e30f;
#pragma unroll
  for (int e = 0; e < NEXP; ++e) { lg[e] = (ga[e] + bg[e]) * invT; mx = fmaxf(mx, lg[e]); }
  float psum = 0.f, pr[NEXP];
#pragma unroll
  for (int e = 0; e < NEXP; ++e) { pr[e] = expf(lg[e] - mx); psum += pr[e]; }

  float eff[NEXP];
#pragma unroll
  for (int e = 0; e < NEXP; ++e) {
    const float* sg = sigs + e * 16;
    float dot = 0.f, sn = 0.f;
#pragma unroll
    for (int i = 0; i < 16; ++i) { dot += ph[i] * sg[i]; sn += sg[i] * sg[i]; }
    sn = fmaxf(sqrtf(sn), 1e-12f);
    float match = (dot / (nrm * sn) + 1.f) * 0.5f;
    eff[e] = (pr[e] / psum) * match;
  }

  int selmask = 0;
#pragma unroll
  for (int t = 0; t < KSEL; ++t) {
    int bi = 0; float bv = -1e30f;
#pragma unroll
    for (int e = 0; e < NEXP; ++e) {
      bool ok = !((selmask >> e) & 1);
      if (ok && eff[e] > bv) { bv = eff[e]; bi = e; }
    }
    selmask |= (1 << bi);
  }
  float wsum = 0.f, wv[NEXP];
#pragma unroll
  for (int e = 0; e < NEXP; ++e) {
    wv[e] = ((selmask >> e) & 1) ? eff[e] : 0.f;
    wsum += wv[e];
  }
  float inv = 1.f / (wsum + 1e-8f);
  if (lane == 0) {
#pragma unroll
    for (int e = 0; e < NEXP; ++e) wts[n * NEXP + e] = wv[e] * inv;
    selmask_g[n] = selmask;
  }
}

// ---------------- deterministic sorted list build (1 block per expert) ----------------

__global__ void listbuild_kernel(const int* __restrict__ selmask_g,
                                 const float* __restrict__ wts,
                                 int* __restrict__ cnt, int* __restrict__ base,
                                 int* __restrict__ list, int* __restrict__ slot_map,
                                 float* __restrict__ wrow) {
  const int e = blockIdx.x;      // 0..7
  const int t = threadIdx.x;     // 0..255, each owns 16 consecutive tokens
  __shared__ int cntT[256][NEXP];
  __shared__ int totAll[NEXP];
  __shared__ int sc[256];

  int msk[16];
  int c8[NEXP];
#pragma unroll
  for (int f = 0; f < NEXP; ++f) c8[f] = 0;
#pragma unroll
  for (int i = 0; i < 16; ++i) {
    msk[i] = selmask_g[t * 16 + i];
#pragma unroll
    for (int f = 0; f < NEXP; ++f) c8[f] += (msk[i] >> f) & 1;
  }
#pragma unroll
  for (int f = 0; f < NEXP; ++f) cntT[t][f] = c8[f];
  __syncthreads();

  if (t < NEXP) {
    int s = 0;
    for (int j = 0; j < 256; ++j) s += cntT[j][t];
    totAll[t] = s;
  }
  __syncthreads();

  if (e == 0 && t == 0) {
    int r = 0;
    for (int f = 0; f < NEXP; ++f) { cnt[f] = totAll[f]; base[f] = r; r += totAll[f]; }
  }
  int gbase = 0;
  for (int f = 0; f < e; ++f) gbase += totAll[f];

  // exclusive prefix over threads for expert e
  sc[t] = c8[e];
  __syncthreads();
  for (int off = 1; off < 256; off <<= 1) {
    int v = (t >= off) ? sc[t - off] : 0;
    __syncthreads();
    sc[t] += v;
    __syncthreads();
  }
  int p = sc[t] - c8[e];

#pragma unroll
  for (int i = 0; i < 16; ++i) {
    const int n = t * 16 + i;
    const int m = msk[i];
    if ((m >> e) & 1) {
      list[e * TOK + p] = n;
      const int rank = __popc(m & ((1 << e) - 1));
      slot_map[n * KSEL + rank] = gbase + p;
      wrow[gbase + p] = wts[n * NEXP + e];
      ++p;
    }
  }
}

// ---------------- GEMM1: per expert, sorted gathered rows ----------------
// hbuf[base[e]+p, col] = bf16( wrow * relu( x[list[p],:] @ W1[e][:,col] + b1[e,col] ) )

__global__ void gemm1_kernel(const uint16_t* __restrict__ xbf,
                             const uint16_t* __restrict__ W1T,
                             const int* __restrict__ cnt,
                             const int* __restrict__ base,
                             const int* __restrict__ list,
                             const float* __restrict__ wrow,
                             const float* __restrict__ b1,
                             uint16_t* __restrict__ hbuf) {
  __shared__ __attribute__((aligned(16))) uint16_t smA[128 * 64];
  __shared__ __attribute__((aligned(16))) uint16_t smB[128 * 64];
  const int e  = blockIdx.z;
  const int ce = cnt[e];
  const int tileM = blockIdx.y * 128;
  if (tileM >= ce) return;
  const int be    = base[e];
  const int tileN = blockIdx.x * 128;
  const int tid = threadIdx.x, lane = tid & 63, wid = tid >> 6;
  const int wr = wid >> 1, wc = wid & 1;
  const int* liste = list + e * TOK;

  const uint16_t* srcA[4]; const uint16_t* srcB[4]; uint32_t lof[4];
#pragma unroll
  for (int j = 0; j < 4; ++j) {
    const int f   = (wid * 4 + j) * 64 + lane;
    const int row = f >> 3;
    const int s8  = (f & 7) ^ (row & 7);
    int p = tileM + row; p = p < ce ? p : ce - 1;
    srcA[j] = xbf + (size_t)liste[p] * DIM + s8 * 8;
    srcB[j] = W1T + ((size_t)e * HID + tileN + row) * DIM + s8 * 8;
    lof[j]  = (wid * 4 + j) * 1024;
  }

  f32x4 acc[4][4];
#pragma unroll
  for (int m = 0; m < 4; ++m)
#pragma unroll
    for (int n = 0; n < 4; ++n) acc[m][n] = (f32x4){0.f, 0.f, 0.f, 0.f};

  for (int k0 = 0; k0 < DIM; k0 += 64) {
#pragma unroll
    for (int j = 0; j < 4; ++j) {
      GLD16(srcA[j] + k0, (char*)smA + lof[j]);
      GLD16(srcB[j] + k0, (char*)smB + lof[j]);
    }
    __syncthreads();
#pragma unroll
    for (int kk = 0; kk < 2; ++kk) {
      bf16x8 av[4], bv[4];
#pragma unroll
      for (int m = 0; m < 4; ++m) {
        const int row = wr * 64 + m * 16 + (lane & 15);
        const int g   = (kk * 4 + (lane >> 4)) ^ (row & 7);
        av[m] = *(const bf16x8*)(smA + row * 64 + g * 8);
      }
#pragma unroll
      for (int n = 0; n < 4; ++n) {
        const int row = wc * 64 + n * 16 + (lane & 15);
        const int g   = (kk * 4 + (lane >> 4)) ^ (row & 7);
        bv[n] = *(const bf16x8*)(smB + row * 64 + g * 8);
      }
#pragma unroll
      for (int m = 0; m < 4; ++m)
#pragma unroll
        for (int n = 0; n < 4; ++n)
          acc[m][n] = __builtin_amdgcn_mfma_f32_16x16x32_bf16(av[m], bv[n], acc[m][n], 0, 0, 0);
    }
    __syncthreads();
  }

  const float* b1e = b1 + (size_t)e * HID;
#pragma unroll
  for (int m = 0; m < 4; ++m)
#pragma unroll
    for (int r = 0; r < 4; ++r) {
      const int p = tileM + wr * 64 + m * 16 + ((lane >> 4) << 2) + r;
      if (p < ce) {
        const float w = wrow[be + p];
        uint16_t* orow = hbuf + (size_t)(be + p) * HID;
#pragma unroll
        for (int nf = 0; nf < 4; ++nf) {
          const int col = tileN + wc * 64 + nf * 16 + (lane & 15);
          float v = acc[m][nf][r] + b1e[col];
          v = v > 0.f ? v : 0.f;
          orow[col] = f2bf(v * w);
        }
      }
    }
}

// ---------------- GEMM2: per expert, compact in / compact out (no atomics) ----------------
// obuf[base[e]+p, col] = bf16( hbuf[base[e]+p, :] @ W2[e][:, col] )

__global__ void gemm2_kernel(const uint16_t* __restrict__ hbuf,
                             const uint16_t* __restrict__ W2T,
                             const int* __restrict__ cnt,
                             const int* __restrict__ base,
                             uint16_t* __restrict__ obuf) {
  __shared__ __attribute__((aligned(16))) uint16_t smA[128 * 64];
  __shared__ __attribute__((aligned(16))) uint16_t smB[128 * 64];
  const int e  = blockIdx.z;
  const int ce = cnt[e];
  const int tileM = blockIdx.y * 128;
  if (tileM >= ce) return;
  const int be    = base[e];
  const int tileN = blockIdx.x * 128;
  const int tid = threadIdx.x, lane = tid & 63, wid = tid >> 6;
  const int wr = wid >> 1, wc = wid & 1;

  const uint16_t* srcA[4]; const uint16_t* srcB[4]; uint32_t lof[4];
#pragma unroll
  for (int j = 0; j < 4; ++j) {
    const int f   = (wid * 4 + j) * 64 + lane;
    const int row = f >> 3;
    const int s8  = (f & 7) ^ (row & 7);
    srcA[j] = hbuf + (size_t)(be + tileM + row) * HID + s8 * 8;
    srcB[j] = W2T + (size_t)(tileN + row) * (NEXP * HID) + e * HID + s8 * 8;
    lof[j]  = (wid * 4 + j) * 1024;
  }

  f32x4 acc[4][4];
#pragma unroll
  for (int m = 0; m < 4; ++m)
#pragma unroll
    for (int n = 0; n < 4; ++n) acc[m][n] = (f32x4){0.f, 0.f, 0.f, 0.f};

  for (int k0 = 0; k0 < HID; k0 += 64) {
#pragma unroll
    for (int j = 0; j < 4; ++j) {
      GLD16(srcA[j] + k0, (char*)smA + lof[j]);
      GLD16(srcB[j] + k0, (char*)smB + lof[j]);
    }
    __syncthreads();
#pragma unroll
    for (int kk = 0; kk < 2; ++kk) {
      bf16x8 av[4], bv[4];
#pragma unroll
      for (int m = 0; m < 4; ++m) {
        const int row = wr * 64 + m * 16 + (lane & 15);
        const int g   = (kk * 4 + (lane >> 4)) ^ (row & 7);
        av[m] = *(const bf16x8*)(smA + row * 64 + g * 8);
      }
#pragma unroll
      for (int n = 0; n < 4; ++n) {
        const int row = wc * 64 + n * 16 + (lane & 15);
        const int g   = (kk * 4 + (lane >> 4)) ^ (row & 7);
        bv[n] = *(const bf16x8*)(smB + row * 64 + g * 8);
      }
#pragma unroll
      for (int m = 0; m < 4; ++m)
#pragma unroll
        for (int n = 0; n < 4; ++n)
          acc[m][n] = __builtin_amdgcn_mfma_f32_16x16x32_bf16(av[m], bv[n], acc[m][n], 0, 0, 0);
    }
    __syncthreads();
  }

#pragma unroll
  for (int m = 0; m < 4; ++m)
#pragma unroll
    for (int r = 0; r < 4; ++r) {
      const int p = tileM + wr * 64 + m * 16 + ((lane >> 4) << 2) + r;
      if (p < ce) {
        uint16_t* orow = obuf + (size_t)(be + p) * ODIM;
#pragma unroll
        for (int nf = 0; nf < 4; ++nf) {
          const int col = tileN + wc * 64 + nf * 16 + (lane & 15);
          orow[col] = f2bf(acc[m][nf][r]);
        }
      }
    }
}

// ---------------- reduce: out[n,:] = sum_e w*b2[e,:] + sum_{k<5} obuf[slot_k,:] ----------------

__global__ void reduce_kernel(const uint16_t* __restrict__ obuf,
                              const int* __restrict__ slot_map,
                              const float* __restrict__ wts,
                              const float* __restrict__ b2,
                              float* __restrict__ out) {
  const int n = blockIdx.x;
  const int t = threadIdx.x;            // 256
  const int c = t * 8;                  // 8 cols per thread

  int slots[KSEL];
#pragma unroll
  for (int k = 0; k < KSEL; ++k) slots[k] = slot_map[n * KSEL + k];
  float w8[NEXP];
#pragma unroll
  for (int e = 0; e < NEXP; ++e) w8[e] = wts[n * NEXP + e];

  float s[8];
#pragma unroll
  for (int j = 0; j < 8; ++j) s[j] = 0.f;
#pragma unroll
  for (int e = 0; e < NEXP; ++e) {
    const float4 b0 = *(const float4*)(b2 + (size_t)e * ODIM + c);
    const float4 b1v = *(const float4*)(b2 + (size_t)e * ODIM + c + 4);
    s[0] += w8[e] * b0.x; s[1] += w8[e] * b0.y; s[2] += w8[e] * b0.z; s[3] += w8[e] * b0.w;
    s[4] += w8[e] * b1v.x; s[5] += w8[e] * b1v.y; s[6] += w8[e] * b1v.z; s[7] += w8[e] * b1v.w;
  }
#pragma unroll
  for (int k = 0; k < KSEL; ++k) {
    const ushort8 v = *(const ushort8*)(obuf + (size_t)slots[k] * ODIM + c);
#pragma unroll
    for (int j = 0; j < 8; ++j) s[j] += bf2f(v[j]);
  }
  float4 o0 = make_float4(s[0], s[1], s[2], s[3]);
  float4 o1 = make_float4(s[4], s[5], s[6], s[7]);
  *(float4*)(out + (size_t)n * ODIM + c) = o0;
  *(float4*)(out + (size_t)n * ODIM + c + 4) = o1;
}

// ---------------- launch ----------------

extern "C" void kernel_launch(void* const* d_in, const int* in_sizes, int n_in,
                              void* d_out, int out_size, void* d_ws, size_t ws_size,
                              hipStream_t stream) {
  const float* x    = (const float*)d_in[0];
  const float* Wg   = (const float*)d_in[1];
  const float* bg   = (const float*)d_in[2];
  const float* Wa   = (const float*)d_in[3];
  const float* ba   = (const float*)d_in[4];
  const float* Wb   = (const float*)d_in[5];
  const float* bb   = (const float*)d_in[6];
  const float* sigs = (const float*)d_in[7];
  const float* W1   = (const float*)d_in[8];
  const float* b1   = (const float*)d_in[9];
  const float* W2   = (const float*)d_in[10];
  const float* b2   = (const float*)d_in[11];
  float* out = (float*)d_out;

  char* ws = (char*)d_ws;
  float*    wts     = (float*)(ws + 0);           //   131072 B
  int*      selmask = (int*)(ws + 131072);        //    16384 B
  int*      cnt     = (int*)(ws + 147456);        //       32 B
  int*      base    = (int*)(ws + 147584);        //       32 B
  int*      slot_map= (int*)(ws + 151552);        //    81920 B
  float*    wrow    = (float*)(ws + 233472);      //    81920 B
  int*      list    = (int*)(ws + 315392);        //   131072 B -> 446464
  uint16_t* xbf     = (uint16_t*)(ws + 446464);   //  16777216 B -> 17223680
  uint16_t* W1T     = (uint16_t*)(ws + 17223680); // 134217728 B -> 151441408
  uint16_t* W2T     = (uint16_t*)(ws + 151441408);// 134217728 B -> 285659136
  uint16_t* hbuf    = (uint16_t*)(ws + 285659136);// 167772160 B -> 453431296
  uint16_t* obuf    = (uint16_t*)(ws + 453431296);//  83886080 B -> 537317376 (512.4 MB)

  cast_x_kernel<<<(TOK * DIM / 4) / 256, 256, 0, stream>>>(x, xbf, TOK * DIM / 4);
  transpose_cast_kernel<<<dim3(HID / 32, DIM / 32, NEXP), dim3(32, 8), 0, stream>>>(
      W1, W1T, DIM, HID, (long)DIM * HID, (long)DIM * HID);
  transpose_cast_kernel<<<dim3(ODIM / 32, (NEXP * HID) / 32, 1), dim3(32, 8), 0, stream>>>(
      W2, W2T, NEXP * HID, ODIM, 0, 0);
  routing_kernel<<<TOK, 64, 0, stream>>>(x, Wg, bg, Wa, ba, Wb, bb, sigs, wts, selmask);
  listbuild_kernel<<<NEXP, 256, 0, stream>>>(selmask, wts, cnt, base, list, slot_map, wrow);

  gemm1_kernel<<<dim3(HID / 128, TOK / 128, NEXP), 256, 0, stream>>>(
      xbf, W1T, cnt, base, list, wrow, b1, hbuf);
  gemm2_kernel<<<dim3(ODIM / 128, TOK / 128, NEXP), 256, 0, stream>>>(
      hbuf, W2T, cnt, base, obuf);
  reduce_kernel<<<TOK, 256, 0, stream>>>(obuf, slot_map, wts, b2, out);
}